// Round 4
// baseline (836.555 us; speedup 1.0000x reference)
//
#include <hip/hip_runtime.h>
#include <hip/hip_bf16.h>

namespace {
constexpr int kB = 4;
constexpr int kC = 512;
constexpr int kH = 128;
constexpr int kW = 128;
constexpr int kCQK = 64;
constexpr int kL = kH * kW;   // 16384
constexpr int kO = 640;       // rows: [0,64)=Wq, [64,128)=Wk, [128,640)=Wv

// workspace layout (float offsets)
constexpr size_t OFF_WALL = 0;                          // wpk: 640*512*2 bf16
constexpr size_t OFF_BALL = (size_t)kO * kC;            // 640
constexpr size_t OFF_QKV  = OFF_BALL + kO;              // B*640*L fp32
constexpr size_t OFF_E    = OFF_QKV + (size_t)kB * kO * kL;  // B*H*W*256 fp32
constexpr size_t WS_FLOATS = OFF_E + (size_t)kB * kH * kW * 256;

typedef __attribute__((ext_vector_type(8))) short bf16x8;
typedef __attribute__((ext_vector_type(4))) float f32x4;

__device__ __forceinline__ unsigned short f32_to_bf16_rn(float f) {
  unsigned u = __float_as_uint(f);
  unsigned r = (u + 0x7FFFu + ((u >> 16) & 1u)) >> 16;
  return (unsigned short)r;
}
__device__ __forceinline__ float bf16_to_f32(unsigned short h) {
  return __uint_as_float(((unsigned)h) << 16);
}
__device__ __forceinline__ unsigned pack_bf16x2(float a, float b) {
  return (unsigned)f32_to_bf16_rn(a) | ((unsigned)f32_to_bf16_rn(b) << 16);
}
}

// ---------------- pack W/bias into bf16 hi/lo planes [640][512] ----------------
__global__ __launch_bounds__(256) void pack_w(
    const float* __restrict__ Wq, const float* __restrict__ bq,
    const float* __restrict__ Wk, const float* __restrict__ bk,
    const float* __restrict__ Wv, const float* __restrict__ bv,
    short* __restrict__ wpk, float* __restrict__ ball) {
  const int r = blockIdx.x;      // 0..639
  const int t = threadIdx.x;     // 256
  const float* src;
  if (r < 64) {
    src = Wq + (size_t)r * kC;
    if (t == 0) ball[r] = bq[r];
  } else if (r < 128) {
    src = Wk + (size_t)(r - 64) * kC;
    if (t == 0) ball[r] = bk[r - 64];
  } else {
    src = Wv + (size_t)(r - 128) * kC;
    if (t == 0) ball[r] = bv[r - 128];
  }
#pragma unroll
  for (int p = 0; p < 2; ++p) {
    const int c = p * 256 + t;
    const float v = src[c];
    const unsigned short h = f32_to_bf16_rn(v);
    const unsigned short l = f32_to_bf16_rn(v - bf16_to_f32(h));
    wpk[(size_t)r * kC + c] = (short)h;
    wpk[(size_t)kO * kC + (size_t)r * kC + c] = (short)l;
  }
}

// ---------------- pack x (one batch): fp32 [c][l] -> bf16 hi/lo [l][c] ----------------
__global__ __launch_bounds__(256) void pack_x(
    const float* __restrict__ x, short* __restrict__ xpk, int b) {
  __shared__ float sT[64][65];
  const int l0 = blockIdx.x * 64;
  const int c0 = blockIdx.y * 64;
  const int t = threadIdx.x;
  const float* xb = x + (size_t)b * kC * kL;
#pragma unroll
  for (int p = 0; p < 4; ++p) {
    const int ch = p * 256 + t;
    const int c = ch >> 4, l4 = (ch & 15) * 4;
    float4 v = *(const float4*)(xb + (size_t)(c0 + c) * kL + l0 + l4);
    sT[c][l4 + 0] = v.x; sT[c][l4 + 1] = v.y; sT[c][l4 + 2] = v.z; sT[c][l4 + 3] = v.w;
  }
  __syncthreads();
#pragma unroll
  for (int p = 0; p < 2; ++p) {
    const int ch = p * 256 + t;
    const int l = ch >> 3, cg = ch & 7;
    short hi[8], lo[8];
#pragma unroll
    for (int j = 0; j < 8; ++j) {
      const float v = sT[cg * 8 + j][l];
      const unsigned short h = f32_to_bf16_rn(v);
      hi[j] = (short)h;
      lo[j] = (short)f32_to_bf16_rn(v - bf16_to_f32(h));
    }
    short* dh = xpk + (size_t)(l0 + l) * kC + c0 + cg * 8;
    *(bf16x8*)dh = *(bf16x8*)hi;
    *(bf16x8*)(dh + (size_t)kL * kC) = *(bf16x8*)lo;
  }
}

// ---------------- projection GEMM via bf16 MFMA, split precision ----------------
__global__ __launch_bounds__(256, 2) void proj_mfma(
    const short* __restrict__ xpk, const short* __restrict__ wpk,
    const float* __restrict__ ball, float* __restrict__ qkv, int b) {
  __shared__ short A_h[128 * 64];
  __shared__ short A_l[128 * 64];
  __shared__ short B_h[128 * 64];
  __shared__ short B_l[128 * 64];
  const int mt = blockIdx.x;          // 0..4
  const int n0 = blockIdx.y * 128;
  const int m0 = mt * 128;
  const bool qk = (mt == 0);
  const int t = threadIdx.x;
  const int wid = t >> 6, lane = t & 63;
  const int wr = wid >> 1, wc = wid & 1;
  const int lr = lane & 15, lg = lane >> 4;

  f32x4 acc[4][4];
#pragma unroll
  for (int i = 0; i < 4; ++i)
#pragma unroll
    for (int j = 0; j < 4; ++j) acc[i][j] = (f32x4)(0.f);

  for (int kt = 0; kt < 8; ++kt) {
    const int k0 = kt * 64;
#pragma unroll
    for (int p = 0; p < 4; ++p) {
      const int ch = p * 256 + t;
      const int row = ch >> 3, kg = ch & 7;
      const short* src = wpk + (size_t)(m0 + row) * kC + k0 + kg * 8;
      const int off = row * 64 + ((kg ^ (row & 7)) << 3);
      *(bf16x8*)&A_h[off] = *(const bf16x8*)src;
      *(bf16x8*)&A_l[off] = *(const bf16x8*)(src + (size_t)kO * kC);
    }
#pragma unroll
    for (int p = 0; p < 4; ++p) {
      const int ch = p * 256 + t;
      const int row = ch >> 3, kg = ch & 7;
      const short* src = xpk + (size_t)(n0 + row) * kC + k0 + kg * 8;
      const int off = row * 64 + ((kg ^ (row & 7)) << 3);
      *(bf16x8*)&B_h[off] = *(const bf16x8*)src;
      if (qk) *(bf16x8*)&B_l[off] = *(const bf16x8*)(src + (size_t)kL * kC);
    }
    __syncthreads();
#pragma unroll
    for (int ks = 0; ks < 2; ++ks) {
      bf16x8 ah[4], al[4], bh[4], bl[4];
#pragma unroll
      for (int mf = 0; mf < 4; ++mf) {
        const int row = wr * 64 + mf * 16 + lr;
        const int kg = ks * 4 + lg;
        const int off = row * 64 + ((kg ^ (row & 7)) << 3);
        ah[mf] = *(const bf16x8*)&A_h[off];
        al[mf] = *(const bf16x8*)&A_l[off];
      }
#pragma unroll
      for (int nf = 0; nf < 4; ++nf) {
        const int row = wc * 64 + nf * 16 + lr;
        const int kg = ks * 4 + lg;
        const int off = row * 64 + ((kg ^ (row & 7)) << 3);
        bh[nf] = *(const bf16x8*)&B_h[off];
        if (qk) bl[nf] = *(const bf16x8*)&B_l[off];
      }
#pragma unroll
      for (int mf = 0; mf < 4; ++mf)
#pragma unroll
        for (int nf = 0; nf < 4; ++nf) {
          acc[mf][nf] = __builtin_amdgcn_mfma_f32_16x16x32_bf16(
              ah[mf], bh[nf], acc[mf][nf], 0, 0, 0);
          acc[mf][nf] = __builtin_amdgcn_mfma_f32_16x16x32_bf16(
              al[mf], bh[nf], acc[mf][nf], 0, 0, 0);
          if (qk)
            acc[mf][nf] = __builtin_amdgcn_mfma_f32_16x16x32_bf16(
                ah[mf], bl[nf], acc[mf][nf], 0, 0, 0);
        }
    }
    __syncthreads();
  }
#pragma unroll
  for (int mf = 0; mf < 4; ++mf) {
#pragma unroll
    for (int r = 0; r < 4; ++r) {
      const int m = m0 + wr * 64 + mf * 16 + lg * 4 + r;
      const float bias = ball[m];
      float* dst = qkv + ((size_t)b * kO + m) * kL + n0 + wc * 64;
#pragma unroll
      for (int nf = 0; nf < 4; ++nf) {
        dst[nf * 16 + lr] = acc[mf][nf][r] + bias;
      }
    }
  }
}

// ---------------- e_row ----------------
__global__ __launch_bounds__(256) void erow_kernel(
    const float* __restrict__ qkv, float* __restrict__ e) {
  __shared__ float sQ[32][128];
  __shared__ float sK[32][128];
  const int bh = blockIdx.x;
  const int b = bh >> 7, h = bh & 127;
  const int t = threadIdx.x;
  const int tx = t & 15, ty = t >> 4;
  float acc[8][8];
#pragma unroll
  for (int i = 0; i < 8; ++i)
#pragma unroll
    for (int j = 0; j < 8; ++j) acc[i][j] = 0.f;

  for (int k0 = 0; k0 < kCQK; k0 += 32) {
#pragma unroll
    for (int p = 0; p < 4; ++p) {
      const int idx = p * 256 + t;
      const int cc = idx >> 5, w4 = (idx & 31) * 4;
      const size_t base = ((size_t)b * kO + k0 + cc) * kL + h * kW + w4;
      *(float4*)&sQ[cc][w4] = *(const float4*)(qkv + base);
      *(float4*)&sK[cc][w4] = *(const float4*)(qkv + base + (size_t)64 * kL);
    }
    __syncthreads();
#pragma unroll
    for (int kk = 0; kk < 32; ++kk) {
      float a[8], bb[8];
      *(float4*)(a + 0) = *(const float4*)&sQ[kk][ty * 8];
      *(float4*)(a + 4) = *(const float4*)&sQ[kk][ty * 8 + 4];
      *(float4*)(bb + 0) = *(const float4*)&sK[kk][tx * 8];
      *(float4*)(bb + 4) = *(const float4*)&sK[kk][tx * 8 + 4];
#pragma unroll
      for (int wi = 0; wi < 8; ++wi)
#pragma unroll
        for (int ii = 0; ii < 8; ++ii) acc[wi][ii] = fmaf(a[wi], bb[ii], acc[wi][ii]);
    }
    __syncthreads();
  }
#pragma unroll
  for (int wi = 0; wi < 8; ++wi) {
    const int w = ty * 8 + wi;
    float* dst = e + (((size_t)b * kH + h) * kW + w) * 256 + tx * 8;
    float4 o0 = {acc[wi][0], acc[wi][1], acc[wi][2], acc[wi][3]};
    float4 o1 = {acc[wi][4], acc[wi][5], acc[wi][6], acc[wi][7]};
    *(float4*)(dst + 0) = o0;
    *(float4*)(dst + 4) = o1;
  }
}

// ---------------- e_col ----------------
__global__ __launch_bounds__(256) void ecol_kernel(
    const float* __restrict__ qkv, float* __restrict__ e) {
  __shared__ float sQ[32][128];
  __shared__ float sK[32][128];
  const int bw = blockIdx.x;
  const int b = bw >> 7, w = bw & 127;
  const int t = threadIdx.x;
  const int tx = t & 15, ty = t >> 4;
  float acc[8][8];
#pragma unroll
  for (int i = 0; i < 8; ++i)
#pragma unroll
    for (int j = 0; j < 8; ++j) acc[i][j] = 0.f;

  for (int k0 = 0; k0 < kCQK; k0 += 32) {
#pragma unroll
    for (int p = 0; p < 16; ++p) {
      const int idx = p * 256 + t;
      const int cc = idx >> 7, hh = idx & 127;
      const size_t base = ((size_t)b * kO + k0 + cc) * kL + hh * kW + w;
      sQ[cc][hh] = qkv[base];
      sK[cc][hh] = qkv[base + (size_t)64 * kL];
    }
    __syncthreads();
#pragma unroll
    for (int kk = 0; kk < 32; ++kk) {
      float a[8], bb[8];
      *(float4*)(a + 0) = *(const float4*)&sQ[kk][ty * 8];
      *(float4*)(a + 4) = *(const float4*)&sQ[kk][ty * 8 + 4];
      *(float4*)(bb + 0) = *(const float4*)&sK[kk][tx * 8];
      *(float4*)(bb + 4) = *(const float4*)&sK[kk][tx * 8 + 4];
#pragma unroll
      for (int hi = 0; hi < 8; ++hi)
#pragma unroll
        for (int ji = 0; ji < 8; ++ji) acc[hi][ji] = fmaf(a[hi], bb[ji], acc[hi][ji]);
    }
    __syncthreads();
  }
  const float NEG_INF = __int_as_float(0xff800000);
#pragma unroll
  for (int hi = 0; hi < 8; ++hi) {
    const int h = ty * 8 + hi;
    float vals[8];
#pragma unroll
    for (int ji = 0; ji < 8; ++ji) {
      const int j = tx * 8 + ji;
      vals[ji] = (j == h) ? NEG_INF : acc[hi][ji];
    }
    float* dst = e + (((size_t)b * kH + h) * kW + w) * 256 + 128 + tx * 8;
    float4 o0 = {vals[0], vals[1], vals[2], vals[3]};
    float4 o1 = {vals[4], vals[5], vals[6], vals[7]};
    *(float4*)(dst + 0) = o0;
    *(float4*)(dst + 4) = o1;
  }
}

// ---------------- softmax; row half -> fp32, col half -> packed bf16 (in place) ----
__global__ __launch_bounds__(256) void softmax_kernel(float* __restrict__ e) {
  const int t = threadIdx.x;
  const int wv = t >> 6, lane = t & 63;
  const size_t pix = (size_t)blockIdx.x * 4 + wv;
  float* p = e + pix * 256 + lane * 4;
  float4 v = *(const float4*)p;
  float m = fmaxf(fmaxf(v.x, v.y), fmaxf(v.z, v.w));
#pragma unroll
  for (int off = 32; off > 0; off >>= 1) m = fmaxf(m, __shfl_xor(m, off, 64));
  float e0 = expf(v.x - m), e1 = expf(v.y - m), e2 = expf(v.z - m), e3 = expf(v.w - m);
  float s = e0 + e1 + e2 + e3;
#pragma unroll
  for (int off = 32; off > 0; off >>= 1) s += __shfl_xor(s, off, 64);
  const float inv = 1.0f / s;
  const float o0 = e0 * inv, o1 = e1 * inv, o2 = e2 * inv, o3 = e3 * inv;
  if (lane < 32) {
    float4 o = {o0, o1, o2, o3};
    *(float4*)p = o;                           // a_row stays fp32
  } else {
    // a_col -> bf16, packed into u16 slots [256 .. 384) of this pixel's row
    const int j = (lane - 32) * 4;
    unsigned lo = pack_bf16x2(o0, o1);
    unsigned hi = pack_bf16x2(o2, o3);
    unsigned short* dst = (unsigned short*)e + pix * 512 + 256 + j;
    *(uint2*)dst = make_uint2(lo, hi);
  }
}

// ---------------- row aggregation (unchanged, fp32) ----------------
__global__ __launch_bounds__(256) void rowagg_kernel(
    const float* __restrict__ qkv, const float* __restrict__ e,
    float* __restrict__ out) {
  __shared__ float sV[32][132];
  __shared__ float sA[32][132];
  const int bh = blockIdx.y;
  const int b = bh >> 7, h = bh & 127;
  const int m0 = blockIdx.x * 128;
  const int t = threadIdx.x;
  const int tx = t & 15, ty = t >> 4;
  float acc[8][8];
#pragma unroll
  for (int i = 0; i < 8; ++i)
#pragma unroll
    for (int j = 0; j < 8; ++j) acc[i][j] = 0.f;

  for (int i0 = 0; i0 < kW; i0 += 32) {
    {
      const int c = t >> 1, ih = (t & 1) * 16;
      const float* src =
          qkv + ((size_t)b * kO + 128 + m0 + c) * kL + h * kW + i0 + ih;
      float tmp[16];
      *(float4*)(tmp + 0)  = *(const float4*)(src + 0);
      *(float4*)(tmp + 4)  = *(const float4*)(src + 4);
      *(float4*)(tmp + 8)  = *(const float4*)(src + 8);
      *(float4*)(tmp + 12) = *(const float4*)(src + 12);
#pragma unroll
      for (int r = 0; r < 16; ++r) sV[ih + r][c] = tmp[r];
    }
#pragma unroll
    for (int p = 0; p < 4; ++p) {
      const int idx = p * 256 + t;
      const int ww = idx >> 3, q = idx & 7;
      float4 av = *(const float4*)(
          e + (((size_t)b * kH + h) * kW + ww) * 256 + i0 + q * 4);
      sA[q * 4 + 0][ww] = av.x;
      sA[q * 4 + 1][ww] = av.y;
      sA[q * 4 + 2][ww] = av.z;
      sA[q * 4 + 3][ww] = av.w;
    }
    __syncthreads();
#pragma unroll
    for (int kk = 0; kk < 32; ++kk) {
      float a[8], bb[8];
      *(float4*)(a + 0) = *(const float4*)&sV[kk][ty * 8];
      *(float4*)(a + 4) = *(const float4*)&sV[kk][ty * 8 + 4];
      *(float4*)(bb + 0) = *(const float4*)&sA[kk][tx * 8];
      *(float4*)(bb + 4) = *(const float4*)&sA[kk][tx * 8 + 4];
#pragma unroll
      for (int ci = 0; ci < 8; ++ci)
#pragma unroll
        for (int wi = 0; wi < 8; ++wi) acc[ci][wi] = fmaf(a[ci], bb[wi], acc[ci][wi]);
    }
    __syncthreads();
  }
#pragma unroll
  for (int ci = 0; ci < 8; ++ci) {
    const int c = m0 + ty * 8 + ci;
    float* dst = out + (((size_t)b * kC + c) * kH + h) * kW + tx * 8;
    float4 o0 = {acc[ci][0], acc[ci][1], acc[ci][2], acc[ci][3]};
    float4 o1 = {acc[ci][4], acc[ci][5], acc[ci][6], acc[ci][7]};
    *(float4*)(dst + 0) = o0;
    *(float4*)(dst + 4) = o1;
  }
}

// ---------------- col aggregation via bf16 MFMA ----------------
// out[b][c][h][w] += sum_j a_col[(h,w)][j] * v[b][c][j][w]
// Block: (b, c-tile 64, h-tile 64, w-tile 4); 4 waves, wave wv owns w = w0+wv.
// K = j, 4 steps of 32. V transpose-staged to LDS bf16 (j-pair packed b32,
// XOR-swizzled); A frags read direct from global bf16 (j-contiguous).
__global__ __launch_bounds__(256) void colagg_mfma(
    const float* __restrict__ qkv, const unsigned short* __restrict__ acol,
    float* __restrict__ out) {
  __shared__ unsigned sV[4 * 64 * 16];   // [w][c][jp] b32 = 2 bf16 (j even, j odd)
  const int gx = blockIdx.x;             // ct(8) + 8*ht(2); c innermost for A L2 reuse
  const int ct = gx & 7, ht = gx >> 3;
  const int c0 = ct * 64, h0 = ht * 64;
  const int w0 = blockIdx.y * 4;
  const int b = blockIdx.z;
  const int t = threadIdx.x;
  const int wv = t >> 6, lane = t & 63;
  const int lr = lane & 15, lg = lane >> 4;
  const int w = w0 + wv;

  f32x4 acc[4][4];   // [mf(c)][nf(h)]
#pragma unroll
  for (int i = 0; i < 4; ++i)
#pragma unroll
    for (int j = 0; j < 4; ++j) acc[i][j] = (f32x4)(0.f);

  const float* vbase = qkv + ((size_t)b * kO + 128 + c0) * kL;  // + c*kL + j*kW + w0

  for (int j0 = 0; j0 < kH; j0 += 32) {
    // ---- stage V: bijective (c,jp) <- (lane, wv, i); 2 float4 loads -> 4 b32 writes
#pragma unroll
    for (int i = 0; i < 4; ++i) {
      const int c = (lane >> 4) + 4 * wv + 16 * i;   // 0..63
      const int jp = lane & 15;                      // j-pair index within step
      const float* src = vbase + (size_t)c * kL + (size_t)(j0 + 2 * jp) * kW + w0;
      float4 v0 = *(const float4*)src;          // j even, w0..w0+3
      float4 v1 = *(const float4*)(src + kW);   // j odd
      const int basep = c * 16 + (jp ^ ((c & 2) << 1));   // XOR bit2 of jp by c-bit1
      sV[0 * 1024 + basep] = pack_bf16x2(v0.x, v1.x);
      sV[1 * 1024 + basep] = pack_bf16x2(v0.y, v1.y);
      sV[2 * 1024 + basep] = pack_bf16x2(v0.z, v1.z);
      sV[3 * 1024 + basep] = pack_bf16x2(v0.w, v1.w);
    }
    __syncthreads();
    // ---- frags ----
    bf16x8 vf[4], af[4];
#pragma unroll
    for (int mf = 0; mf < 4; ++mf) {
      const int c = mf * 16 + lr;
      const int q = lg ^ ((c >> 1) & 1);     // inverse of write swizzle at quad level
      vf[mf] = *(const bf16x8*)&sV[wv * 1024 + c * 16 + 4 * q];
    }
#pragma unroll
    for (int nf = 0; nf < 4; ++nf) {
      const int h = h0 + nf * 16 + lr;
      const unsigned short* asrc =
          acol + (((size_t)b * kH + h) * kW + w) * 512 + 256 + j0 + lg * 8;
      af[nf] = *(const bf16x8*)asrc;
    }
#pragma unroll
    for (int mf = 0; mf < 4; ++mf)
#pragma unroll
      for (int nf = 0; nf < 4; ++nf)
        acc[mf][nf] = __builtin_amdgcn_mfma_f32_16x16x32_bf16(
            vf[mf], af[nf], acc[mf][nf], 0, 0, 0);
    __syncthreads();
  }
  // ---- epilogue: scalar RMW (D: row=c=4lg+r, col=h=lr) ----
#pragma unroll
  for (int mf = 0; mf < 4; ++mf) {
#pragma unroll
    for (int r = 0; r < 4; ++r) {
      const int c = c0 + mf * 16 + lg * 4 + r;
      float* dst = out + (((size_t)b * kC + c) * kH + h0) * kW + w;
#pragma unroll
      for (int nf = 0; nf < 4; ++nf) {
        dst[(nf * 16 + lr) * kW] += acc[mf][nf][r];
      }
    }
  }
}

extern "C" void kernel_launch(void* const* d_in, const int* in_sizes, int n_in,
                              void* d_out, int out_size, void* d_ws, size_t ws_size,
                              hipStream_t stream) {
  (void)in_sizes; (void)n_in; (void)out_size; (void)ws_size;
  const float* x  = (const float*)d_in[0];
  const float* Wq = (const float*)d_in[1];
  const float* bq = (const float*)d_in[2];
  const float* Wk = (const float*)d_in[3];
  const float* bk = (const float*)d_in[4];
  const float* Wv = (const float*)d_in[5];
  const float* bv = (const float*)d_in[6];
  float* out = (float*)d_out;
  float* ws  = (float*)d_ws;

  short* wpk = (short*)(ws + OFF_WALL);
  float* ball = ws + OFF_BALL;
  float* qkv  = ws + OFF_QKV;
  float* e    = ws + OFF_E;
  short* xpk  = (short*)(ws + OFF_E);   // aliases e (used only before e is written)

  pack_w<<<dim3(kO), dim3(256), 0, stream>>>(Wq, bq, Wk, bk, Wv, bv, wpk, ball);
  for (int b = 0; b < kB; ++b) {
    pack_x<<<dim3(kL / 64, kC / 64), dim3(256), 0, stream>>>(x, xpk, b);
    proj_mfma<<<dim3(5, kL / 128), dim3(256), 0, stream>>>(xpk, wpk, ball, qkv, b);
  }
  erow_kernel<<<dim3(kB * kH), dim3(256), 0, stream>>>(qkv, e);
  ecol_kernel<<<dim3(kB * kW), dim3(256), 0, stream>>>(qkv, e);
  softmax_kernel<<<dim3(kB * kH * kW / 4), dim3(256), 0, stream>>>(e);
  rowagg_kernel<<<dim3(kC / 128, kB * kH), dim3(256), 0, stream>>>(qkv, e, out);
  colagg_mfma<<<dim3(16, kW / 4, kB), dim3(256), 0, stream>>>(
      qkv, (const unsigned short*)e, out);
}